// Round 14
// baseline (575.107 us; speedup 1.0000x reference)
//
#include <hip/hip_runtime.h>
#include <hip/hip_cooperative_groups.h>

namespace cg = cooperative_groups;

// z: [16,4096,256] fp32 -> N=65536 rows, d=256
// embedding: [256,1024], cluster_size: [1024], embedding_mean: [256,1024]

#define DECAYC 0.99f
#define EPSQ 1e-5f

typedef unsigned short ushort_t;
typedef __attribute__((ext_vector_type(8))) short bf16x8;
typedef __attribute__((ext_vector_type(4))) float f32x4;
typedef unsigned long long u64;

__device__ __forceinline__ ushort_t f2bf(float x) {
    unsigned u = __float_as_uint(x);
    unsigned r = (u + 0x7FFFu + ((u >> 16) & 1u)) >> 16;   // RNE
    return (ushort_t)r;
}
__device__ __forceinline__ float bf2f(ushort_t h) {
    return __uint_as_float(((unsigned)h) << 16);
}
__device__ __forceinline__ u64 umin64(u64 a, u64 b) { return a < b ? a : b; }

// ---------------- E-side prep (round-7 verbatim: proven in the 299us run) ----------------
__global__ __launch_bounds__(256) void prep_E_kernel(const float* __restrict__ E,
                                                     float* __restrict__ ET,
                                                     float* __restrict__ colnorm,
                                                     ushort_t* __restrict__ Eph,
                                                     ushort_t* __restrict__ Epl,
                                                     int* __restrict__ counts,
                                                     float* __restrict__ lossSum,
                                                     float* __restrict__ psum) {
    int n = blockIdx.x;
    int d = threadIdx.x;
    if (d == 0) counts[n] = 0;
    if (n == 0 && d == 1) lossSum[0] = 0.f;
    psum[n * 256 + d] = 0.f;
    float v = E[d * 1024 + n];
    ET[n * 256 + d] = v;
    ushort_t h = f2bf(v);
    ushort_t l = f2bf(v - bf2f(h));
    size_t pi = ((size_t)(d >> 3) * 1024 + n) * 8 + (d & 7);
    Eph[pi] = h;
    Epl[pi] = l;
    __shared__ float red[256];
    red[d] = v * v;
    __syncthreads();
    for (int o = 128; o > 0; o >>= 1) {
        if (d < o) red[d] += red[d + o];
        __syncthreads();
    }
    if (d == 0) colnorm[n] = red[0];
}

// ---------------- MFMA distance + argmin + fused gather/loss/hist ----------------
// ROUND-0 VERBATIM (proven 142us, VGPR=128, no spill). Round-12 lesson: NO
// device fences in here — per-block __threadfence flushes the per-XCD L2 and
// evicts the L2-resident Eph/Epl panels (+45us, MfmaUtil 31->23).
__global__ __launch_bounds__(256, 2) void dist_mfma_kernel(const float* __restrict__ z,
                                                           const ushort_t* __restrict__ Eph,
                                                           const ushort_t* __restrict__ Epl,
                                                           const float* __restrict__ colnorm,
                                                           const float* __restrict__ ET,
                                                           float* __restrict__ out0,
                                                           float* __restrict__ lossSum,
                                                           int* __restrict__ counts,
                                                           int* __restrict__ idxOut) {
    __shared__ __align__(16) ushort_t Ah[16384];   // slots (kq*64+r)*8, 32 KB
    __shared__ __align__(16) ushort_t Al[16384];
    __shared__ u64 bl[2][64];                      // per-wcol row minima
    __shared__ float zpart[4][64];                 // per-wave ||z||^2 partials
    __shared__ int kArr[64];
    __shared__ float sred[1];

    const int t = threadIdx.x;
    const int lane = t & 63;
    const int w = t >> 6;          // wave 0..3
    const int wrow = w >> 1;       // 0..1 (rows wrow*32..)
    const int wcol = w & 1;        // 0..1 (codes wcol*64.. within chunk)
    const int n16 = lane & 15;
    const int q = lane >> 4;       // 0..3
    const int rowBase = blockIdx.x * 64;

    // ---- one-time: convert 64 z rows to bf16 hi/lo in LDS + ||z||^2 partials ----
    float zsq = 0.f;
#pragma unroll
    for (int i = 0; i < 8; ++i) {
        int s = i * 256 + t;       // slot: kq = s>>6, r = s&63
        int kq = s >> 6;
        int r = s & 63;
        const float* gp = z + (size_t)(rowBase + r) * 256 + kq * 8;
        float4 v0 = *(const float4*)gp;
        float4 v1 = *(const float4*)(gp + 4);
        float vv[8] = {v0.x, v0.y, v0.z, v0.w, v1.x, v1.y, v1.z, v1.w};
        ushort_t hh[8], ll[8];
#pragma unroll
        for (int j = 0; j < 8; ++j) {
            hh[j] = f2bf(vv[j]);
            ll[j] = f2bf(vv[j] - bf2f(hh[j]));
            zsq += vv[j] * vv[j];
        }
        ushort4 h0 = {hh[0], hh[1], hh[2], hh[3]}, h1 = {hh[4], hh[5], hh[6], hh[7]};
        ushort4 l0 = {ll[0], ll[1], ll[2], ll[3]}, l1 = {ll[4], ll[5], ll[6], ll[7]};
        *(ushort4*)&Ah[s * 8] = h0;
        *(ushort4*)&Ah[s * 8 + 4] = h1;
        *(ushort4*)&Al[s * 8] = l0;
        *(ushort4*)&Al[s * 8 + 4] = l1;
    }
    zpart[w][lane] = zsq;          // r = lane for every i
    __syncthreads();

    u64 best[2][4];
#pragma unroll
    for (int rt = 0; rt < 2; ++rt)
#pragma unroll
        for (int reg = 0; reg < 4; ++reg) best[rt][reg] = ~0ull;

    for (int cb = 0; cb < 8; ++cb) {
        const int cBase = cb * 128;
        f32x4 acc[2][4];
#pragma unroll
        for (int rt = 0; rt < 2; ++rt)
#pragma unroll
            for (int ct = 0; ct < 4; ++ct) acc[rt][ct] = (f32x4){0.f, 0.f, 0.f, 0.f};

#pragma unroll
        for (int ks = 0; ks < 8; ++ks) {
            bf16x8 bfh[4], bfl[4];
            const size_t bbase = ((size_t)(ks * 4 + q) * 1024 + cBase + wcol * 64 + n16) * 8;
#pragma unroll
            for (int ct = 0; ct < 4; ++ct) {
                bfh[ct] = *(const bf16x8*)(Eph + bbase + ct * 128);
                bfl[ct] = *(const bf16x8*)(Epl + bbase + ct * 128);
            }
            bf16x8 afh[2], afl[2];
#pragma unroll
            for (int rt = 0; rt < 2; ++rt) {
                int ao = ((ks * 4 + q) * 64 + wrow * 32 + rt * 16 + n16) * 8;
                afh[rt] = *(const bf16x8*)&Ah[ao];
                afl[rt] = *(const bf16x8*)&Al[ao];
            }
#pragma unroll
            for (int rt = 0; rt < 2; ++rt)
#pragma unroll
                for (int ct = 0; ct < 4; ++ct) {
                    acc[rt][ct] = __builtin_amdgcn_mfma_f32_16x16x32_bf16(afh[rt], bfh[ct], acc[rt][ct], 0, 0, 0);
                    acc[rt][ct] = __builtin_amdgcn_mfma_f32_16x16x32_bf16(afh[rt], bfl[ct], acc[rt][ct], 0, 0, 0);
                    acc[rt][ct] = __builtin_amdgcn_mfma_f32_16x16x32_bf16(afl[rt], bfh[ct], acc[rt][ct], 0, 0, 0);
                }
        }

        // lane-local argmin update (no cross-lane work inside the cb loop)
        float cn[4];
#pragma unroll
        for (int ct = 0; ct < 4; ++ct) cn[ct] = colnorm[cBase + wcol * 64 + ct * 16 + n16];
#pragma unroll
        for (int rt = 0; rt < 2; ++rt)
#pragma unroll
            for (int reg = 0; reg < 4; ++reg) {
                u64 b = best[rt][reg];
#pragma unroll
                for (int ct = 0; ct < 4; ++ct) {
                    float dist = cn[ct] - 2.f * acc[rt][ct][reg];
                    unsigned fb = __float_as_uint(dist);
                    unsigned sk = (fb & 0x80000000u) ? ~fb : (fb | 0x80000000u);
                    unsigned code = (unsigned)(cBase + wcol * 64 + ct * 16 + n16);
                    b = umin64(b, ((u64)sk << 32) | code);
                }
                best[rt][reg] = b;
            }
    }

    // one-time cross-lane reduction within each 16-lane col group
#pragma unroll
    for (int rt = 0; rt < 2; ++rt)
#pragma unroll
        for (int reg = 0; reg < 4; ++reg) {
            u64 b = best[rt][reg];
            b = umin64(b, __shfl_xor(b, 1, 64));
            b = umin64(b, __shfl_xor(b, 2, 64));
            b = umin64(b, __shfl_xor(b, 4, 64));
            b = umin64(b, __shfl_xor(b, 8, 64));
            best[rt][reg] = b;
        }
    if (n16 == 0) {
#pragma unroll
        for (int rt = 0; rt < 2; ++rt)
#pragma unroll
            for (int reg = 0; reg < 4; ++reg)
                bl[wcol][wrow * 32 + rt * 16 + q * 4 + reg] = best[rt][reg];
    }
    __syncthreads();

    // ---- epilogue: merge wcol halves, decode key -> code + loss, hist ----
    if (t < 64) {
        u64 b = umin64(bl[0][t], bl[1][t]);
        int k = (int)(unsigned)(b & 0xFFFFFFFFull);
        unsigned sk = (unsigned)(b >> 32);
        unsigned fb = (sk & 0x80000000u) ? (sk ^ 0x80000000u) : ~sk;
        float zn = zpart[0][t] + zpart[1][t] + zpart[2][t] + zpart[3][t];
        float dmin = __uint_as_float(fb) + zn;
        idxOut[rowBase + t] = k;
        kArr[t] = k;
        atomicAdd(counts + k, 1);
        float v = dmin;
#pragma unroll
        for (int o = 32; o > 0; o >>= 1) v += __shfl_down(v, o, 64);
        if (t == 0) sred[0] = v;
    }
    __syncthreads();
    if (t == 0) atomicAdd(lossSum, sred[0]);

    // ---- gather z_q: wave w writes rows w*16..w*16+15 (no z re-read) ----
#pragma unroll
    for (int i = 0; i < 16; ++i) {
        int r = w * 16 + i;
        int k = kArr[r];
        float4 qv = *(const float4*)(ET + (size_t)k * 256 + lane * 4);
        *(float4*)(out0 + (size_t)(rowBase + r) * 256 + lane * 4) = qv;
    }
}

// ---------------- cooperative fused tail: prefix/csn -> scatter -> segsum -> finalE ----------------
// Round-13 (resubmitted after broker timeout; untested hypothesis). The ~155us
// tail was 4 small latency-bound kernels + 4 launch gaps, none individually in
// top-5. One cooperative kernel (512 blocks x 256, co-resident), grid.sync at
// phase boundaries. Fences happen at sync points with tiny dirty sets
// (offsets/sorted/psum) and nothing concurrent to disturb — unlike r12's
// per-block fence inside the MFMA hot loop.
__global__ __launch_bounds__(256) void coop_tail_kernel(const float* __restrict__ z,
                                                        const int* __restrict__ idx,
                                                        const float* __restrict__ cluster_size,
                                                        const float* __restrict__ lossSum,
                                                        const float* __restrict__ embedding_mean,
                                                        int* __restrict__ counts,
                                                        int* __restrict__ offsets,
                                                        int* __restrict__ cursor,
                                                        int* __restrict__ sorted,
                                                        float* __restrict__ psum,
                                                        float* __restrict__ out1,
                                                        float* __restrict__ out2,
                                                        float* __restrict__ out3,
                                                        float* __restrict__ out4,
                                                        float* __restrict__ nOut) {
    cg::grid_group grid = cg::this_grid();
    const int t = threadIdx.x;
    const int b = blockIdx.x;          // 512 blocks
    const int lane = t & 63;
    const int w = t >> 6;

    // ---- phase A: block 0 scans counts -> offsets, csn, n, loss; zero cursor ----
    if (b == 0) {
        __shared__ int ss[256];
        __shared__ float fb2[4];
        const int base = t * 4;
        int c4[4];
        int s0 = 0;
#pragma unroll
        for (int j = 0; j < 4; ++j) {
            c4[j] = counts[base + j];
            s0 += c4[j];
        }
        ss[t] = s0;
        __syncthreads();
        for (int off = 1; off < 256; off <<= 1) {
            int v = (t >= off) ? ss[t - off] : 0;
            __syncthreads();
            ss[t] += v;
            __syncthreads();
        }
        int run = ss[t] - s0;
        float fsum = 0.f;
#pragma unroll
        for (int j = 0; j < 4; ++j) {
            offsets[base + j] = run;
            run += c4[j];
            cursor[base + j] = 0;
            float cnv = cluster_size[base + j] * DECAYC + (1.f - DECAYC) * (float)c4[j];
            out3[base + j] = cnv;
            fsum += cnv;
        }
        if (t == 255) offsets[1024] = run;
#pragma unroll
        for (int o = 32; o > 0; o >>= 1) fsum += __shfl_down(fsum, o, 64);
        if (lane == 0) fb2[w] = fsum;
        __syncthreads();
        if (t == 0) {
            nOut[0] = fb2[0] + fb2[1] + fb2[2] + fb2[3];
            out1[0] = 0.25f * lossSum[0] / 16777216.0f;
        }
    }
    __threadfence();
    grid.sync();

    // ---- phase B: scatter row ids into code-sorted order (first 256 blocks) ----
    if (b < 256) {
        int i = b * 256 + t;
        int k = idx[i];
        int pos = atomicAdd(cursor + k, 1);
        sorted[offsets[k] + pos] = i;
    }
    __threadfence();
    grid.sync();

    // ---- phase C: balanced chunked segsum (r7-verbatim body; 512 blocks) ----
    {
        const int j0 = (b * 4 + w) * 32;
        const int row_v = sorted[j0 + (lane & 31)];
        const int k_v = idx[row_v];
        float4 acc = {0.f, 0.f, 0.f, 0.f};
        int kcur = __shfl(k_v, 0, 64);
#pragma unroll 4
        for (int i = 0; i < 32; ++i) {
            int row = __shfl(row_v, i, 64);
            int k = __shfl(k_v, i, 64);
            if (k != kcur) {                   // wave-uniform branch
                float* p = psum + (size_t)kcur * 256 + lane * 4;
                atomicAdd(p + 0, acc.x);
                atomicAdd(p + 1, acc.y);
                atomicAdd(p + 2, acc.z);
                atomicAdd(p + 3, acc.w);
                acc = (float4){0.f, 0.f, 0.f, 0.f};
                kcur = k;
            }
            float4 v = *(const float4*)(z + (size_t)row * 256 + lane * 4);
            acc.x += v.x; acc.y += v.y; acc.z += v.z; acc.w += v.w;
        }
        float* p = psum + (size_t)kcur * 256 + lane * 4;
        atomicAdd(p + 0, acc.x);
        atomicAdd(p + 1, acc.y);
        atomicAdd(p + 2, acc.z);
        atomicAdd(p + 3, acc.w);
    }
    __threadfence();
    grid.sync();

    // ---- phase D: embedding_mean_new + embedding_new ----
    for (int e = b * 256 + t; e < 262144; e += 131072) {
        int d = e >> 10;
        int k = e & 1023;
        float es = psum[(size_t)k * 256 + d];  // L2-resident 1MB
        float emn = embedding_mean[e] * DECAYC + (1.f - DECAYC) * es;
        out4[e] = emn;
        float n = nOut[0];
        float c = out3[k];
        float cs = (c + EPSQ) / (n + 1024.f * EPSQ) * n;
        out2[e] = emn / cs;
    }
}

extern "C" void kernel_launch(void* const* d_in, const int* in_sizes, int n_in,
                              void* d_out, int out_size, void* d_ws, size_t ws_size,
                              hipStream_t stream) {
    const float* z = (const float*)d_in[0];
    const float* E = (const float*)d_in[1];
    const float* cluster_size = (const float*)d_in[2];
    const float* embedding_mean = (const float*)d_in[3];

    float* out0 = (float*)d_out;        // z_q_st
    float* out1 = out0 + 16777216;      // vq_loss
    float* out2 = out1 + 1;             // embedding_new
    float* out3 = out2 + 262144;        // cluster_size_new
    float* out4 = out3 + 1024;          // embedding_mean_new

    // ws layout (float units)
    float* ws = (float*)d_ws;
    float* colnorm = ws;                         // 1024
    int* idx = (int*)(ws + 1024);                // 65536
    int* counts = (int*)(ws + 66560);            // 1024  (zeroed in prep_E)
    float* lossSum = ws + 67584;                 // 1     (zeroed in prep_E)
    float* nOut = ws + 67585;                    // 1
    float* ET = ws + 67588;                      // 262144 fp32 [k][d]
    ushort_t* Eph = (ushort_t*)(ws + 329732);    // 262144 ushort
    ushort_t* Epl = (ushort_t*)(ws + 460804);    // 262144 ushort
    float* psum = ws + 591876;                   // 262144 [k][d] (zeroed in prep_E)
    int* sorted = (int*)(ws + 2689028);          // 65536
    int* offsets = (int*)(ws + 2754564);         // 1025
    int* cursor = (int*)(ws + 2755592);          // 1024

    prep_E_kernel<<<1024, 256, 0, stream>>>(E, ET, colnorm, Eph, Epl, counts, lossSum, psum);
    dist_mfma_kernel<<<1024, 256, 0, stream>>>(z, Eph, Epl, colnorm, ET,
                                               out0, lossSum, counts, idx);
    void* cargs[] = {(void*)&z, (void*)&idx, (void*)&cluster_size, (void*)&lossSum,
                     (void*)&embedding_mean, (void*)&counts, (void*)&offsets,
                     (void*)&cursor, (void*)&sorted, (void*)&psum,
                     (void*)&out1, (void*)&out2, (void*)&out3, (void*)&out4,
                     (void*)&nOut};
    hipLaunchCooperativeKernel((const void*)coop_tail_kernel, dim3(512), dim3(256),
                               cargs, 0, stream);
}

// Round 16
// 296.875 us; speedup vs baseline: 1.9372x; 1.9372x over previous
//
#include <hip/hip_runtime.h>

// z: [16,4096,256] fp32 -> N=65536 rows, d=256
// embedding: [256,1024], cluster_size: [1024], embedding_mean: [256,1024]

#define DECAYC 0.99f
#define EPSQ 1e-5f

typedef unsigned short ushort_t;
typedef __attribute__((ext_vector_type(8))) short bf16x8;
typedef __attribute__((ext_vector_type(4))) float f32x4;
typedef unsigned long long u64;

__device__ __forceinline__ ushort_t f2bf(float x) {
    unsigned u = __float_as_uint(x);
    unsigned r = (u + 0x7FFFu + ((u >> 16) & 1u)) >> 16;   // RNE
    return (ushort_t)r;
}
__device__ __forceinline__ float bf2f(ushort_t h) {
    return __uint_as_float(((unsigned)h) << 16);
}
__device__ __forceinline__ u64 umin64(u64 a, u64 b) { return a < b ? a : b; }

// ---------------- E-side prep (round-7 verbatim + cursor zeroing) ----------------
__global__ __launch_bounds__(256) void prep_E_kernel(const float* __restrict__ E,
                                                     float* __restrict__ ET,
                                                     float* __restrict__ colnorm,
                                                     ushort_t* __restrict__ Eph,
                                                     ushort_t* __restrict__ Epl,
                                                     int* __restrict__ counts,
                                                     float* __restrict__ lossSum,
                                                     float* __restrict__ psum,
                                                     int* __restrict__ cursor) {
    int n = blockIdx.x;
    int d = threadIdx.x;
    if (d == 0) counts[n] = 0;
    if (d == 2) cursor[n] = 0;
    if (n == 0 && d == 1) lossSum[0] = 0.f;
    psum[n * 256 + d] = 0.f;
    float v = E[d * 1024 + n];
    ET[n * 256 + d] = v;
    ushort_t h = f2bf(v);
    ushort_t l = f2bf(v - bf2f(h));
    size_t pi = ((size_t)(d >> 3) * 1024 + n) * 8 + (d & 7);
    Eph[pi] = h;
    Epl[pi] = l;
    __shared__ float red[256];
    red[d] = v * v;
    __syncthreads();
    for (int o = 128; o > 0; o >>= 1) {
        if (d < o) red[d] += red[d + o];
        __syncthreads();
    }
    if (d == 0) colnorm[n] = red[0];
}

// ---------------- MFMA distance + argmin + fused gather/loss/hist ----------------
// ROUND-0 VERBATIM (proven 142us, VGPR=128, no spill). r12/r14 lessons: NO
// device fences / grid syncs anywhere near this kernel — both cost 45-330us
// on gfx950's non-coherent per-XCD L2s.
__global__ __launch_bounds__(256, 2) void dist_mfma_kernel(const float* __restrict__ z,
                                                           const ushort_t* __restrict__ Eph,
                                                           const ushort_t* __restrict__ Epl,
                                                           const float* __restrict__ colnorm,
                                                           const float* __restrict__ ET,
                                                           float* __restrict__ out0,
                                                           float* __restrict__ lossSum,
                                                           int* __restrict__ counts,
                                                           int* __restrict__ idxOut) {
    __shared__ __align__(16) ushort_t Ah[16384];   // slots (kq*64+r)*8, 32 KB
    __shared__ __align__(16) ushort_t Al[16384];
    __shared__ u64 bl[2][64];                      // per-wcol row minima
    __shared__ float zpart[4][64];                 // per-wave ||z||^2 partials
    __shared__ int kArr[64];
    __shared__ float sred[1];

    const int t = threadIdx.x;
    const int lane = t & 63;
    const int w = t >> 6;          // wave 0..3
    const int wrow = w >> 1;       // 0..1 (rows wrow*32..)
    const int wcol = w & 1;        // 0..1 (codes wcol*64.. within chunk)
    const int n16 = lane & 15;
    const int q = lane >> 4;       // 0..3
    const int rowBase = blockIdx.x * 64;

    // ---- one-time: convert 64 z rows to bf16 hi/lo in LDS + ||z||^2 partials ----
    float zsq = 0.f;
#pragma unroll
    for (int i = 0; i < 8; ++i) {
        int s = i * 256 + t;       // slot: kq = s>>6, r = s&63
        int kq = s >> 6;
        int r = s & 63;
        const float* gp = z + (size_t)(rowBase + r) * 256 + kq * 8;
        float4 v0 = *(const float4*)gp;
        float4 v1 = *(const float4*)(gp + 4);
        float vv[8] = {v0.x, v0.y, v0.z, v0.w, v1.x, v1.y, v1.z, v1.w};
        ushort_t hh[8], ll[8];
#pragma unroll
        for (int j = 0; j < 8; ++j) {
            hh[j] = f2bf(vv[j]);
            ll[j] = f2bf(vv[j] - bf2f(hh[j]));
            zsq += vv[j] * vv[j];
        }
        ushort4 h0 = {hh[0], hh[1], hh[2], hh[3]}, h1 = {hh[4], hh[5], hh[6], hh[7]};
        ushort4 l0 = {ll[0], ll[1], ll[2], ll[3]}, l1 = {ll[4], ll[5], ll[6], ll[7]};
        *(ushort4*)&Ah[s * 8] = h0;
        *(ushort4*)&Ah[s * 8 + 4] = h1;
        *(ushort4*)&Al[s * 8] = l0;
        *(ushort4*)&Al[s * 8 + 4] = l1;
    }
    zpart[w][lane] = zsq;          // r = lane for every i
    __syncthreads();

    u64 best[2][4];
#pragma unroll
    for (int rt = 0; rt < 2; ++rt)
#pragma unroll
        for (int reg = 0; reg < 4; ++reg) best[rt][reg] = ~0ull;

    for (int cb = 0; cb < 8; ++cb) {
        const int cBase = cb * 128;
        f32x4 acc[2][4];
#pragma unroll
        for (int rt = 0; rt < 2; ++rt)
#pragma unroll
            for (int ct = 0; ct < 4; ++ct) acc[rt][ct] = (f32x4){0.f, 0.f, 0.f, 0.f};

#pragma unroll
        for (int ks = 0; ks < 8; ++ks) {
            bf16x8 bfh[4], bfl[4];
            const size_t bbase = ((size_t)(ks * 4 + q) * 1024 + cBase + wcol * 64 + n16) * 8;
#pragma unroll
            for (int ct = 0; ct < 4; ++ct) {
                bfh[ct] = *(const bf16x8*)(Eph + bbase + ct * 128);
                bfl[ct] = *(const bf16x8*)(Epl + bbase + ct * 128);
            }
            bf16x8 afh[2], afl[2];
#pragma unroll
            for (int rt = 0; rt < 2; ++rt) {
                int ao = ((ks * 4 + q) * 64 + wrow * 32 + rt * 16 + n16) * 8;
                afh[rt] = *(const bf16x8*)&Ah[ao];
                afl[rt] = *(const bf16x8*)&Al[ao];
            }
#pragma unroll
            for (int rt = 0; rt < 2; ++rt)
#pragma unroll
                for (int ct = 0; ct < 4; ++ct) {
                    acc[rt][ct] = __builtin_amdgcn_mfma_f32_16x16x32_bf16(afh[rt], bfh[ct], acc[rt][ct], 0, 0, 0);
                    acc[rt][ct] = __builtin_amdgcn_mfma_f32_16x16x32_bf16(afh[rt], bfl[ct], acc[rt][ct], 0, 0, 0);
                    acc[rt][ct] = __builtin_amdgcn_mfma_f32_16x16x32_bf16(afl[rt], bfh[ct], acc[rt][ct], 0, 0, 0);
                }
        }

        // lane-local argmin update (no cross-lane work inside the cb loop)
        float cn[4];
#pragma unroll
        for (int ct = 0; ct < 4; ++ct) cn[ct] = colnorm[cBase + wcol * 64 + ct * 16 + n16];
#pragma unroll
        for (int rt = 0; rt < 2; ++rt)
#pragma unroll
            for (int reg = 0; reg < 4; ++reg) {
                u64 b = best[rt][reg];
#pragma unroll
                for (int ct = 0; ct < 4; ++ct) {
                    float dist = cn[ct] - 2.f * acc[rt][ct][reg];
                    unsigned fb = __float_as_uint(dist);
                    unsigned sk = (fb & 0x80000000u) ? ~fb : (fb | 0x80000000u);
                    unsigned code = (unsigned)(cBase + wcol * 64 + ct * 16 + n16);
                    b = umin64(b, ((u64)sk << 32) | code);
                }
                best[rt][reg] = b;
            }
    }

    // one-time cross-lane reduction within each 16-lane col group
#pragma unroll
    for (int rt = 0; rt < 2; ++rt)
#pragma unroll
        for (int reg = 0; reg < 4; ++reg) {
            u64 b = best[rt][reg];
            b = umin64(b, __shfl_xor(b, 1, 64));
            b = umin64(b, __shfl_xor(b, 2, 64));
            b = umin64(b, __shfl_xor(b, 4, 64));
            b = umin64(b, __shfl_xor(b, 8, 64));
            best[rt][reg] = b;
        }
    if (n16 == 0) {
#pragma unroll
        for (int rt = 0; rt < 2; ++rt)
#pragma unroll
            for (int reg = 0; reg < 4; ++reg)
                bl[wcol][wrow * 32 + rt * 16 + q * 4 + reg] = best[rt][reg];
    }
    __syncthreads();

    // ---- epilogue: merge wcol halves, decode key -> code + loss, hist ----
    if (t < 64) {
        u64 b = umin64(bl[0][t], bl[1][t]);
        int k = (int)(unsigned)(b & 0xFFFFFFFFull);
        unsigned sk = (unsigned)(b >> 32);
        unsigned fb = (sk & 0x80000000u) ? (sk ^ 0x80000000u) : ~sk;
        float zn = zpart[0][t] + zpart[1][t] + zpart[2][t] + zpart[3][t];
        float dmin = __uint_as_float(fb) + zn;
        idxOut[rowBase + t] = k;
        kArr[t] = k;
        atomicAdd(counts + k, 1);
        float v = dmin;
#pragma unroll
        for (int o = 32; o > 0; o >>= 1) v += __shfl_down(v, o, 64);
        if (t == 0) sred[0] = v;
    }
    __syncthreads();
    if (t == 0) atomicAdd(lossSum, sred[0]);

    // ---- gather z_q: wave w writes rows w*16..w*16+15 (no z re-read) ----
#pragma unroll
    for (int i = 0; i < 16; ++i) {
        int r = w * 16 + i;
        int k = kArr[r];
        float4 qv = *(const float4*)(ET + (size_t)k * 256 + lane * 4);
        *(float4*)(out0 + (size_t)(rowBase + r) * 256 + lane * 4) = qv;
    }
}

// ---------------- scatter with per-block redundant prefix scan ----------------
// Round-15 (resubmitted after broker timeout; untested hypothesis): replaces
// the single-block prefix_csn (whole-GPU serialization: 1 block, 20 barriers)
// + scatter_sort pair. Each of the 256 blocks loads the 4KB counts array
// (L2-hot), scans it in LDS (offsets never touch global), then scatters its
// 256 rows via the global cursor. No cross-block sync, no device fences —
// just redundant cheap work.
__global__ __launch_bounds__(256) void scatter_scan_kernel(const int* __restrict__ idx,
                                                           const int* __restrict__ counts,
                                                           int* __restrict__ cursor,
                                                           int* __restrict__ sorted) {
    __shared__ int ss[256];
    __shared__ int offL[1024];
    const int t = threadIdx.x;
    const int base = t * 4;
    int c4[4];
    int s0 = 0;
#pragma unroll
    for (int j = 0; j < 4; ++j) {
        c4[j] = counts[base + j];
        s0 += c4[j];
    }
    ss[t] = s0;
    __syncthreads();
    for (int off = 1; off < 256; off <<= 1) {
        int v = (t >= off) ? ss[t - off] : 0;
        __syncthreads();
        ss[t] += v;
        __syncthreads();
    }
    int run = ss[t] - s0;              // exclusive prefix of this thread's group
#pragma unroll
    for (int j = 0; j < 4; ++j) {
        offL[base + j] = run;
        run += c4[j];
    }
    __syncthreads();

    int i = blockIdx.x * 256 + t;
    int k = idx[i];
    int pos = atomicAdd(cursor + k, 1);
    sorted[offL[k] + pos] = i;
}

// ---------------- balanced chunked segsum (r7 VERBATIM — proven ~30us) ----------------
__global__ __launch_bounds__(256) void segsum_atomic_kernel(const float* __restrict__ z,
                                                            const int* __restrict__ sorted,
                                                            const int* __restrict__ idx,
                                                            float* __restrict__ psum) {
    const int t = threadIdx.x;
    const int lane = t & 63;
    const int w = t >> 6;
    const int j0 = (blockIdx.x * 4 + w) * 32;
    const int row_v = sorted[j0 + (lane & 31)];
    const int k_v = idx[row_v];
    float4 acc = {0.f, 0.f, 0.f, 0.f};
    int kcur = __shfl(k_v, 0, 64);
#pragma unroll 4
    for (int i = 0; i < 32; ++i) {
        int row = __shfl(row_v, i, 64);
        int k = __shfl(k_v, i, 64);
        if (k != kcur) {                       // wave-uniform branch
            float* p = psum + (size_t)kcur * 256 + lane * 4;
            atomicAdd(p + 0, acc.x);
            atomicAdd(p + 1, acc.y);
            atomicAdd(p + 2, acc.z);
            atomicAdd(p + 3, acc.w);
            acc = (float4){0.f, 0.f, 0.f, 0.f};
            kcur = k;
        }
        float4 v = *(const float4*)(z + (size_t)row * 256 + lane * 4);
        acc.x += v.x; acc.y += v.y; acc.z += v.z; acc.w += v.w;
    }
    float* p = psum + (size_t)kcur * 256 + lane * 4;
    atomicAdd(p + 0, acc.x);
    atomicAdd(p + 1, acc.y);
    atomicAdd(p + 2, acc.z);
    atomicAdd(p + 3, acc.w);
}

// ---------------- finalE2: csn + n + loss folded in (no prefix_csn kernel) ----------------
// n = sum(cluster_size_new) = 0.99*sum(cluster_size) + 0.01*sum(counts), and
// sum(counts) == 65536 always. Each block redundantly reduces the 4KB
// cluster_size array (L2-hot) for n; csn computed per-element from counts.
// Blocks 0..3 (d==0) write out3; thread 0 writes the loss scalar.
__global__ __launch_bounds__(256) void finalE2_kernel(const float* __restrict__ embedding_mean,
                                                      const float* __restrict__ psum,
                                                      const float* __restrict__ cluster_size,
                                                      const int* __restrict__ counts,
                                                      const float* __restrict__ lossSum,
                                                      float* __restrict__ out1,
                                                      float* __restrict__ out2,
                                                      float* __restrict__ out3,
                                                      float* __restrict__ out4) {
    const int t = threadIdx.x;
    const int tid = blockIdx.x * 256 + t;
    __shared__ float red[256];
    float s = cluster_size[t] + cluster_size[t + 256] +
              cluster_size[t + 512] + cluster_size[t + 768];
    red[t] = s;
    __syncthreads();
    for (int o = 128; o > 0; o >>= 1) {
        if (t < o) red[t] += red[t + o];
        __syncthreads();
    }
    const float n = red[0] * DECAYC + (1.f - DECAYC) * 65536.0f;

    const int d = tid >> 10;
    const int k = tid & 1023;
    float c = cluster_size[k] * DECAYC + (1.f - DECAYC) * (float)counts[k];
    if (d == 0) out3[k] = c;
    float es = psum[(size_t)k * 256 + d];      // uncoalesced but L2-resident (1MB)
    float emn = embedding_mean[tid] * DECAYC + (1.f - DECAYC) * es;
    out4[tid] = emn;
    float cs = (c + EPSQ) / (n + 1024.f * EPSQ) * n;
    out2[tid] = emn / cs;
    if (tid == 0) out1[0] = 0.25f * lossSum[0] / 16777216.0f;
}

extern "C" void kernel_launch(void* const* d_in, const int* in_sizes, int n_in,
                              void* d_out, int out_size, void* d_ws, size_t ws_size,
                              hipStream_t stream) {
    const float* z = (const float*)d_in[0];
    const float* E = (const float*)d_in[1];
    const float* cluster_size = (const float*)d_in[2];
    const float* embedding_mean = (const float*)d_in[3];

    float* out0 = (float*)d_out;        // z_q_st
    float* out1 = out0 + 16777216;      // vq_loss
    float* out2 = out1 + 1;             // embedding_new
    float* out3 = out2 + 262144;        // cluster_size_new
    float* out4 = out3 + 1024;          // embedding_mean_new

    // ws layout (float units)
    float* ws = (float*)d_ws;
    float* colnorm = ws;                         // 1024
    int* idx = (int*)(ws + 1024);                // 65536
    int* counts = (int*)(ws + 66560);            // 1024  (zeroed in prep_E)
    float* lossSum = ws + 67584;                 // 1     (zeroed in prep_E)
    float* ET = ws + 67588;                      // 262144 fp32 [k][d]
    ushort_t* Eph = (ushort_t*)(ws + 329732);    // 262144 ushort
    ushort_t* Epl = (ushort_t*)(ws + 460804);    // 262144 ushort
    float* psum = ws + 591876;                   // 262144 [k][d] (zeroed in prep_E)
    int* sorted = (int*)(ws + 2689028);          // 65536
    int* cursor = (int*)(ws + 2755592);          // 1024  (zeroed in prep_E)

    prep_E_kernel<<<1024, 256, 0, stream>>>(E, ET, colnorm, Eph, Epl, counts, lossSum,
                                            psum, cursor);
    dist_mfma_kernel<<<1024, 256, 0, stream>>>(z, Eph, Epl, colnorm, ET,
                                               out0, lossSum, counts, idx);
    scatter_scan_kernel<<<256, 256, 0, stream>>>(idx, counts, cursor, sorted);
    segsum_atomic_kernel<<<512, 256, 0, stream>>>(z, sorted, idx, psum);
    finalE2_kernel<<<1024, 256, 0, stream>>>(embedding_mean, psum, cluster_size, counts,
                                             lossSum, out1, out2, out3, out4);
}